// Round 1
// baseline (743.556 us; speedup 1.0000x reference)
//
#include <hip/hip_runtime.h>

#define T_STEPS 1024
#define BATCH   1024
#define NS      64

// One wave (64 lanes) per batch. Lane s owns output state s.
// Exp-domain forward recurrence:
//   u[s] = exp(alpha[s] - c);  u_new[s] = (sum_p E[s][p] * u[p]) * exp(em_t[s])
// with E[s][p] = exp(trans[s][p]) held in 64 VGPRs per lane.
// Renormalize by wave-max every 4 steps to stay inside fp32 range.
__launch_bounds__(64, 1)
__global__ void crf_forward_kernel(const float* __restrict__ em,     // [T, B, S]
                                   const int*   __restrict__ seqlen, // [B]
                                   const float* __restrict__ start,  // [S]
                                   const float* __restrict__ stop,   // [S]
                                   const float* __restrict__ trans,  // [S, S]
                                   float*       __restrict__ out) {  // [B]
    __shared__ __align__(16) float lds_u[NS];

    const int b = blockIdx.x;
    const int s = threadIdx.x;          // 0..63
    const int L = seqlen[b];            // uniform across wave -> scalar

    // E row for this lane: e[p] = exp(trans[s][p]). Vectorized 16B loads.
    float e[NS];
    {
        const float4* t4 = reinterpret_cast<const float4*>(trans + s * NS);
        #pragma unroll
        for (int i = 0; i < NS / 4; ++i) {
            float4 tv = t4[i];
            e[4 * i + 0] = __expf(tv.x);
            e[4 * i + 1] = __expf(tv.y);
            e[4 * i + 2] = __expf(tv.z);
            e[4 * i + 3] = __expf(tv.w);
        }
    }

    // alpha_0 = start + em[0]
    float alpha0 = start[s] + em[(size_t)b * NS + s];
    float m = alpha0;
    #pragma unroll
    for (int o = 32; o > 0; o >>= 1) m = fmaxf(m, __shfl_xor(m, o, 64));
    float c = m;                 // running log-offset (wave-uniform)
    float u = __expf(alpha0 - m);

    // Prefetch em for t=1 (always a valid address; unused if L==1).
    float em_next = em[((size_t)1 * BATCH + b) * NS + s];

    for (int t = 1; t < L; ++t) {
        float em_cur = em_next;
        int tn = (t + 1 < T_STEPS) ? (t + 1) : (T_STEPS - 1);
        em_next = em[((size_t)tn * BATCH + b) * NS + s];

        // all-gather u across the wave via LDS (single wave per block:
        // DS pipe processes same-wave ops in order; no block barrier needed)
        lds_u[s] = u;
        __builtin_amdgcn_sched_barrier(0);

        float a0 = 0.f, a1 = 0.f, a2 = 0.f, a3 = 0.f;
        const float4* u4 = reinterpret_cast<const float4*>(lds_u);
        #pragma unroll
        for (int i = 0; i < NS / 4; ++i) {
            float4 uv = u4[i];
            a0 = fmaf(e[4 * i + 0], uv.x, a0);
            a1 = fmaf(e[4 * i + 1], uv.y, a1);
            a2 = fmaf(e[4 * i + 2], uv.z, a2);
            a3 = fmaf(e[4 * i + 3], uv.w, a3);
        }
        __builtin_amdgcn_sched_barrier(0);
        float ssum = (a0 + a1) + (a2 + a3);
        u = ssum * __expf(em_cur);

        // periodic renormalization (uniform branch)
        if ((t & 3) == 3) {
            float mm = u;
            #pragma unroll
            for (int o = 32; o > 0; o >>= 1) mm = fmaxf(mm, __shfl_xor(mm, o, 64));
            c += __logf(mm);
            u = u / mm;
        }
    }

    // log_Z = log(sum_s u[s] * exp(stop[s])) + c
    float v = u * __expf(stop[s]);
    #pragma unroll
    for (int o = 32; o > 0; o >>= 1) v += __shfl_xor(v, o, 64);
    if (s == 0) out[b] = __logf(v) + c;
}

extern "C" void kernel_launch(void* const* d_in, const int* in_sizes, int n_in,
                              void* d_out, int out_size, void* d_ws, size_t ws_size,
                              hipStream_t stream) {
    const float* em     = (const float*)d_in[0]; // [T, B, S]
    const int*   seqlen = (const int*)  d_in[1]; // [B]
    const float* start  = (const float*)d_in[2]; // [S]
    const float* stop   = (const float*)d_in[3]; // [S]
    const float* trans  = (const float*)d_in[4]; // [S, S]
    float*       out    = (float*)d_out;         // [B]

    crf_forward_kernel<<<BATCH, NS, 0, stream>>>(em, seqlen, start, stop, trans, out);
}

// Round 2
// 730.358 us; speedup vs baseline: 1.0181x; 1.0181x over previous
//
#include <hip/hip_runtime.h>

#define T_STEPS 1024
#define BATCH   1024
#define NS      64

typedef __attribute__((ext_vector_type(8))) short bf16x8;   // 8 bf16 (4 VGPRs)
typedef __attribute__((ext_vector_type(4))) float f32x4;    // MFMA C/D

// round-to-nearest-even float -> bf16 bits (used once, for E)
__device__ __forceinline__ unsigned f2bf_rne(float x) {
    union { float f; unsigned u; } v; v.f = x;
    return (v.u + 0x7FFFu + ((v.u >> 16) & 1u)) >> 16;
}

// pack two floats to bf16x2 by truncation: one v_perm_b32
__device__ __forceinline__ unsigned pack_bf16_trunc(float a, float b) {
    union { float f; unsigned u; } x, y; x.f = a; y.f = b;
    // D.b0=S1.b2, D.b1=S1.b3 (low short = a>>16); D.b2=S0.b2, D.b3=S0.b3 (high short = b>>16)
    return __builtin_amdgcn_perm(y.u, x.u, 0x07060302u);
}

// One wave per block; 16 batches per wave (N dim of MFMA).
// Exp-domain recurrence on matrix cores:
//   U[s][b] <- (sum_p E[s][p] * U[p][b]) * exp(em_t[s][b]),   E = exp(trans)
// E held as 8 A-fragments (4 s-tiles x 2 k-segments) in VGPRs.
// U lives in C/D fragment layout; C->B layout transform via tiny LDS round trip.
// Per-batch renorm (max + rcp) every 4 steps keeps fp32/bf16 in range.
__launch_bounds__(64, 1)
__global__ void crf_mfma_kernel(const float* __restrict__ em,     // [T, B, S]
                                const int*   __restrict__ seqlen, // [B]
                                const float* __restrict__ start,  // [S]
                                const float* __restrict__ stop,   // [S]
                                const float* __restrict__ trans,  // [S, S]
                                float*       __restrict__ out) {  // [B]
    // bf16 U staging: 16 batch rows, stride 80 shorts (160 B) ->
    // writes (b64) and reads (b128) both conflict-free, 16B-aligned reads.
    __shared__ short u_lds[16 * 80];

    const int l = threadIdx.x;     // 0..63
    const int q = l >> 4;          // quad 0..3
    const int b = l & 15;          // batch column within wave
    const int bbase = blockIdx.x * 16;
    const int gb = bbase + b;

    const int L = seqlen[gb];
    int maxL = L;
    #pragma unroll
    for (int o = 1; o < 64; o <<= 1) maxL = max(maxL, __shfl_xor(maxL, o, 64));

    // ---- E = exp(trans) as A-operand fragments, loaded once ----
    // A-frag (s-tile st, k-seg kq): lane holds A[m][k], m = st*16 + (l&15),
    // k (=p) = kq*32 + q*8 + j, j = 0..7.
    bf16x8 Ef[4][2];
    #pragma unroll
    for (int st = 0; st < 4; ++st) {
        const int s = st * 16 + (l & 15);
        #pragma unroll
        for (int kq = 0; kq < 2; ++kq) {
            const int p0 = kq * 32 + q * 8;
            const float4 t0 = *(const float4*)(trans + s * NS + p0);
            const float4 t1 = *(const float4*)(trans + s * NS + p0 + 4);
            bf16x8 f;
            f[0] = (short)f2bf_rne(__expf(t0.x));
            f[1] = (short)f2bf_rne(__expf(t0.y));
            f[2] = (short)f2bf_rne(__expf(t0.z));
            f[3] = (short)f2bf_rne(__expf(t0.w));
            f[4] = (short)f2bf_rne(__expf(t1.x));
            f[5] = (short)f2bf_rne(__expf(t1.y));
            f[6] = (short)f2bf_rne(__expf(t1.z));
            f[7] = (short)f2bf_rne(__expf(t1.w));
            Ef[st][kq] = f;
        }
    }

    // ---- per-lane em loader in C-fragment layout: s = st*16 + q*4 + r ----
    auto load_em = [&](int t, float (&dst)[16]) {
        const size_t base = ((size_t)t * BATCH + gb) * NS;
        #pragma unroll
        for (int st = 0; st < 4; ++st) {
            const float4 v = *(const float4*)(em + base + st * 16 + q * 4);
            dst[st * 4 + 0] = v.x; dst[st * 4 + 1] = v.y;
            dst[st * 4 + 2] = v.z; dst[st * 4 + 3] = v.w;
        }
    };

    // ---- init: alpha0 = start + em0; U = exp(alpha0 - c) ----
    float U[16];
    float c;
    {
        float a0[16];
        #pragma unroll
        for (int st = 0; st < 4; ++st) {
            const int s0 = st * 16 + q * 4;
            const float4 e0 = *(const float4*)(em + (size_t)gb * NS + s0);
            const float4 sv = *(const float4*)(start + s0);
            a0[st * 4 + 0] = sv.x + e0.x; a0[st * 4 + 1] = sv.y + e0.y;
            a0[st * 4 + 2] = sv.z + e0.z; a0[st * 4 + 3] = sv.w + e0.w;
        }
        float mx = a0[0];
        #pragma unroll
        for (int i = 1; i < 16; ++i) mx = fmaxf(mx, a0[i]);
        mx = fmaxf(mx, __shfl_xor(mx, 16, 64));   // per-batch max (4 q-lanes)
        mx = fmaxf(mx, __shfl_xor(mx, 32, 64));
        c = mx;
        #pragma unroll
        for (int i = 0; i < 16; ++i) U[i] = __expf(a0[i] - mx);
    }

    // ---- one recurrence step ----
    auto step = [&](int t, float (&emc)[16], float (&emn)[16]) {
        // prefetch em[t+1] (clamped; unused values are cndmask'd away)
        const int tn = (t + 1 < T_STEPS) ? (t + 1) : (T_STEPS - 1);
        load_em(tn, emn);

        // emission factors for this step (off the LDS critical path)
        float ex[16];
        #pragma unroll
        for (int i = 0; i < 16; ++i) ex[i] = __expf(emc[i]);

        // C-layout -> LDS (bf16): lane's 4 groups of 4 consecutive states
        short* row = u_lds + b * 80;
        #pragma unroll
        for (int st = 0; st < 4; ++st) {
            uint2 w;
            w.x = pack_bf16_trunc(U[st * 4 + 0], U[st * 4 + 1]);
            w.y = pack_bf16_trunc(U[st * 4 + 2], U[st * 4 + 3]);
            *(uint2*)(row + st * 16 + q * 4) = w;   // ds_write_b64
        }
        asm volatile("" ::: "memory");  // keep write->read program order (same-wave DS pipe is in-order)

        // B-operand fragments: lane needs U[p][b], p = kq*32 + q*8 + j
        const bf16x8 B0 = *(const bf16x8*)(row + 0  + q * 8);   // ds_read_b128
        const bf16x8 B1 = *(const bf16x8*)(row + 32 + q * 8);

        const bool act = (t < L);
        #pragma unroll
        for (int st = 0; st < 4; ++st) {
            f32x4 acc = __builtin_amdgcn_mfma_f32_16x16x32_bf16(Ef[st][0], B0, (f32x4)0.f, 0, 0, 0);
            acc       = __builtin_amdgcn_mfma_f32_16x16x32_bf16(Ef[st][1], B1, acc, 0, 0, 0);
            #pragma unroll
            for (int r = 0; r < 4; ++r) {
                const float cand = acc[r] * ex[st * 4 + r];
                U[st * 4 + r] = act ? cand : U[st * 4 + r];   // freeze ended sequences
            }
        }
    };

    // ---- renorm every 4 steps: per-batch max -> scale, no division ----
    auto renorm = [&]() {
        float m = U[0];
        #pragma unroll
        for (int i = 1; i < 16; ++i) m = fmaxf(m, U[i]);
        m = fmaxf(m, __shfl_xor(m, 16, 64));
        m = fmaxf(m, __shfl_xor(m, 32, 64));
        const float r = __builtin_amdgcn_rcpf(m);
        c += __logf(m);
        #pragma unroll
        for (int i = 0; i < 16; ++i) U[i] *= r;
    };

    // ---- main loop, unrolled by 4 with em double-buffer ----
    float emA[16], emB[16];
    load_em((T_STEPS > 1) ? 1 : 0, emA);
    for (int t = 1; t < maxL; t += 4) {
        step(t,     emA, emB);
        step(t + 1, emB, emA);
        step(t + 2, emA, emB);
        step(t + 3, emB, emA);
        renorm();
    }

    // ---- epilogue: log_Z[b] = log(sum_s U[s][b] * exp(stop[s])) + c ----
    float accv = 0.f;
    #pragma unroll
    for (int st = 0; st < 4; ++st) {
        const int s0 = st * 16 + q * 4;
        const float4 sv = *(const float4*)(stop + s0);
        accv += U[st * 4 + 0] * __expf(sv.x);
        accv += U[st * 4 + 1] * __expf(sv.y);
        accv += U[st * 4 + 2] * __expf(sv.z);
        accv += U[st * 4 + 3] * __expf(sv.w);
    }
    accv += __shfl_xor(accv, 16, 64);
    accv += __shfl_xor(accv, 32, 64);
    if (l < 16) out[bbase + l] = __logf(accv) + c;
}

extern "C" void kernel_launch(void* const* d_in, const int* in_sizes, int n_in,
                              void* d_out, int out_size, void* d_ws, size_t ws_size,
                              hipStream_t stream) {
    const float* em     = (const float*)d_in[0]; // [T, B, S]
    const int*   seqlen = (const int*)  d_in[1]; // [B]
    const float* start  = (const float*)d_in[2]; // [S]
    const float* stop   = (const float*)d_in[3]; // [S]
    const float* trans  = (const float*)d_in[4]; // [S, S]
    float*       out    = (float*)d_out;         // [B]

    crf_mfma_kernel<<<BATCH / 16, 64, 0, stream>>>(em, seqlen, start, stop, trans, out);
}

// Round 3
// 634.820 us; speedup vs baseline: 1.1713x; 1.1505x over previous
//
#include <hip/hip_runtime.h>

#define T_STEPS 1024
#define BATCH   1024
#define NS      64

// One wave per batch chain; lane s owns state s. Exp-domain recurrence:
//   u[s] <- (sum_p E[s][p] * u[p]) * exp(em_t[s]),  E = exp(trans), row in VGPRs.
// Cross-lane broadcast of u via bf16x2 pack + 32 v_readlane -> SGPRs; the
// bf16->f32 "unpack" (<<16 / &0xFFFF0000) is uniform, so it lands on SALU.
// No LDS anywhere (round 1/2 were DS-pipe / LDS-latency bound).
__global__ __launch_bounds__(64)
__attribute__((amdgpu_waves_per_eu(1, 1)))
void crf_fwd_readlane(const float* __restrict__ em,     // [T, B, S]
                      const int*   __restrict__ seqlen, // [B]
                      const float* __restrict__ start,  // [S]
                      const float* __restrict__ stop,   // [S]
                      const float* __restrict__ trans,  // [S, S]
                      float*       __restrict__ out) {  // [B]
    const int b = blockIdx.x;
    const int s = threadIdx.x;          // 0..63
    const int L = seqlen[b];            // wave-uniform
    const int total = L - 1;            // number of recurrence steps

    // ---- E row for this lane, f32, pinned in VGPRs (round-1 spill fix) ----
    float e[NS];
    {
        const float4* t4 = reinterpret_cast<const float4*>(trans + s * NS);
        #pragma unroll
        for (int i = 0; i < NS / 4; ++i) {
            float4 t = t4[i];
            e[4 * i + 0] = __expf(t.x);
            e[4 * i + 1] = __expf(t.y);
            e[4 * i + 2] = __expf(t.z);
            e[4 * i + 3] = __expf(t.w);
        }
    }
    #pragma unroll
    for (int i = 0; i < NS; ++i) asm volatile("" : "+v"(e[i]));  // no remat/spill

    // ---- init: u = exp(start + em0), c = 0 (alpha0 range ~[-12,12], safe) ----
    float u = __expf(start[s] + em[(size_t)b * NS + s]);
    float c = 0.f;

    const float*  gp      = em + (size_t)b * NS + s;
    const size_t  TSTRIDE = (size_t)BATCH * NS;

    // one recurrence step: u(t+1) from u(t) and em value (already loaded)
    auto step = [&](float em_t) {
        // pack (u[2k], u[2k+1]) as bf16x2 on even lanes (round-half via +0x8000)
        unsigned ui = __float_as_uint(u) + 0x8000u;
        unsigned pi = __builtin_amdgcn_mov_dpp(ui, 0xB1, 0xF, 0xF, true); // lane^1
        unsigned pk = __builtin_amdgcn_perm(pi, ui, 0x07060302u); // lo=bf16(own), hi=bf16(partner)
        float a0 = 0.f, a1 = 0.f, a2 = 0.f, a3 = 0.f;
        #pragma unroll
        for (int k = 0; k < 16; ++k) {
            const unsigned p0 = __builtin_amdgcn_readlane(pk, 4 * k);     // (u[4k],   u[4k+1])
            const unsigned p1 = __builtin_amdgcn_readlane(pk, 4 * k + 2); // (u[4k+2], u[4k+3])
            a0 = fmaf(e[4 * k + 0], __uint_as_float(p0 << 16),        a0);
            a1 = fmaf(e[4 * k + 1], __uint_as_float(p0 & 0xFFFF0000u), a1);
            a2 = fmaf(e[4 * k + 2], __uint_as_float(p1 << 16),        a2);
            a3 = fmaf(e[4 * k + 3], __uint_as_float(p1 & 0xFFFF0000u), a3);
        }
        u = ((a0 + a1) + (a2 + a3)) * __expf(em_t);
    };

    // wave-uniform renorm: ANY uniform positive scale works (state spread is
    // bounded), so lane 0's u replaces a 6-stage shuffle-max chain.
    auto renorm = [&]() {
        float m = __uint_as_float(__builtin_amdgcn_readlane(__float_as_uint(u), 0));
        m = fmaxf(m, 1e-30f);
        u *= __builtin_amdgcn_rcpf(m);
        c += __logf(m);
    };

    // ---- prefetch em for steps t=1..4 ----
    float emq[4];
    #pragma unroll
    for (int j = 0; j < 4; ++j) {
        int t = 1 + j; if (t > T_STEPS - 1) t = T_STEPS - 1;
        emq[j] = gp[(size_t)t * TSTRIDE];
    }

    int done = 0;
    while (done + 4 <= total) {
        // prefetch next group's em (t = done+5 .. done+8, clamped)
        float emn[4];
        #pragma unroll
        for (int j = 0; j < 4; ++j) {
            int t = done + 5 + j; if (t > T_STEPS - 1) t = T_STEPS - 1;
            emn[j] = gp[(size_t)t * TSTRIDE];
        }

        renorm();
        step(emq[0]); step(emq[1]); step(emq[2]); step(emq[3]);

        #pragma unroll
        for (int j = 0; j < 4; ++j) emq[j] = emn[j];
        done += 4;
    }

    const int tail = total - done;  // 0..3; emq[0..tail-1] already prefetched
    if (tail > 0) {
        renorm();
        for (int j = 0; j < tail; ++j) step(emq[j]);
    }

    // ---- epilogue: log_Z = log(sum_s u[s]*exp(stop[s])) + c ----
    float v = u * __expf(stop[s]);
    #pragma unroll
    for (int o = 1; o < 64; o <<= 1) v += __shfl_xor(v, o, 64);
    if (s == 0) out[b] = __logf(v) + c;
}

extern "C" void kernel_launch(void* const* d_in, const int* in_sizes, int n_in,
                              void* d_out, int out_size, void* d_ws, size_t ws_size,
                              hipStream_t stream) {
    const float* em     = (const float*)d_in[0]; // [T, B, S]
    const int*   seqlen = (const int*)  d_in[1]; // [B]
    const float* start  = (const float*)d_in[2]; // [S]
    const float* stop   = (const float*)d_in[3]; // [S]
    const float* trans  = (const float*)d_in[4]; // [S, S]
    float*       out    = (float*)d_out;         // [B]

    crf_fwd_readlane<<<BATCH, NS, 0, stream>>>(em, seqlen, start, stop, trans, out);
}

// Round 4
// 524.535 us; speedup vs baseline: 1.4176x; 1.2103x over previous
//
#include <hip/hip_runtime.h>

#define T_STEPS 1024
#define BATCH   1024
#define NS      64

// One wave per batch chain; lane s owns state s. Exp-domain recurrence:
//   u[s] <- (sum_p E[s][p] * u[p]) * exp(em_t[s]),  E = exp(trans) in 64 VGPRs.
// Gather of u across lanes: 64 v_readlane -> SGPRs, batched 32 at a time with
// sched_barrier between gather and consume so every SGPR read is >=32 instrs
// after its write (kills the VALU->SGPR RAW hazard bubbles that bounded r3).
// All transcendentals (exp of emissions, renorm rcp/log) are off the u-chain.
__global__ __launch_bounds__(64)
__attribute__((amdgpu_waves_per_eu(1, 1)))
void crf_fwd_v4(const float* __restrict__ em,     // [T, B, S]
                const int*   __restrict__ seqlen, // [B]
                const float* __restrict__ start,  // [S]
                const float* __restrict__ stop,   // [S]
                const float* __restrict__ trans,  // [S, S]
                float*       __restrict__ out) {  // [B]
    const int b = blockIdx.x;
    const int s = threadIdx.x;          // 0..63
    const int L = seqlen[b];            // wave-uniform
    const int total = L - 1;            // recurrence steps

    // ---- E row for this lane, f32, pinned in VGPRs ----
    float e[NS];
    {
        const float4* t4 = reinterpret_cast<const float4*>(trans + s * NS);
        #pragma unroll
        for (int i = 0; i < NS / 4; ++i) {
            float4 t = t4[i];
            e[4 * i + 0] = __expf(t.x);
            e[4 * i + 1] = __expf(t.y);
            e[4 * i + 2] = __expf(t.z);
            e[4 * i + 3] = __expf(t.w);
        }
    }
    #pragma unroll
    for (int i = 0; i < NS; ++i) asm volatile("" : "+v"(e[i]));

    // ---- init ----
    float u = __expf(start[s] + em[(size_t)b * NS + s]);
    float c = 0.f;
    const float*  gp = em + (size_t)b * NS + s;
    const size_t  TS = (size_t)BATCH * NS;

    // one step; rn=true folds a renormalization into this step's ex.
    // (step is linear in u, so scaling the output by r == scaling ex by r;
    //  the rcp/log then overlap with the gather instead of serializing.)
    auto step = [&](float ex, bool rn) {
        const unsigned ub = __float_as_uint(u);
        if (rn) {
            float m = __uint_as_float(__builtin_amdgcn_readlane(ub, 0));
            m = fmaxf(m, 1e-30f);
            ex *= __builtin_amdgcn_rcpf(m);
            c += __logf(m);
        }
        float a0 = 0.f, a1 = 0.f, a2 = 0.f, a3 = 0.f;
        #pragma unroll
        for (int h = 0; h < 2; ++h) {
            unsigned g[32];
            #pragma unroll
            for (int j = 0; j < 32; ++j)
                g[j] = __builtin_amdgcn_readlane(ub, 32 * h + j);
            __builtin_amdgcn_sched_barrier(0);   // all reads >=32 instrs after writes
            #pragma unroll
            for (int j = 0; j < 8; ++j) {
                a0 = fmaf(e[32 * h + 4 * j + 0], __uint_as_float(g[4 * j + 0]), a0);
                a1 = fmaf(e[32 * h + 4 * j + 1], __uint_as_float(g[4 * j + 1]), a1);
                a2 = fmaf(e[32 * h + 4 * j + 2], __uint_as_float(g[4 * j + 2]), a2);
                a3 = fmaf(e[32 * h + 4 * j + 3], __uint_as_float(g[4 * j + 3]), a3);
            }
        }
        u = ((a0 + a1) + (a2 + a3)) * ex;
    };

    // ---- main loop: unroll 8, em prefetched one group (8 steps) ahead ----
    float emq[8];
    #pragma unroll
    for (int j = 0; j < 8; ++j) {
        int t = 1 + j; if (t > T_STEPS - 1) t = T_STEPS - 1;
        emq[j] = gp[(size_t)t * TS];
    }

    int done = 0;
    while (done + 8 <= total) {
        float emn[8];
        #pragma unroll
        for (int j = 0; j < 8; ++j) {
            int t = done + 9 + j; if (t > T_STEPS - 1) t = T_STEPS - 1;
            emn[j] = gp[(size_t)t * TS];
        }
        float ex[8];
        #pragma unroll
        for (int j = 0; j < 8; ++j) ex[j] = __expf(emq[j]);

        step(ex[0], true);  step(ex[1], false); step(ex[2], false); step(ex[3], false);
        step(ex[4], true);  step(ex[5], false); step(ex[6], false); step(ex[7], false);

        #pragma unroll
        for (int j = 0; j < 8; ++j) emq[j] = emn[j];
        done += 8;
    }

    // tail: 0..7 remaining steps, em already prefetched in emq
    const int tail = total - done;
    for (int j = 0; j < tail; ++j)
        step(__expf(emq[j]), (j & 3) == 0);

    // ---- epilogue: log_Z = log(sum_s u[s]*exp(stop[s])) + c ----
    float v = u * __expf(stop[s]);
    #pragma unroll
    for (int o = 1; o < 64; o <<= 1) v += __shfl_xor(v, o, 64);
    if (s == 0) out[b] = __logf(v) + c;
}

extern "C" void kernel_launch(void* const* d_in, const int* in_sizes, int n_in,
                              void* d_out, int out_size, void* d_ws, size_t ws_size,
                              hipStream_t stream) {
    const float* em     = (const float*)d_in[0]; // [T, B, S]
    const int*   seqlen = (const int*)  d_in[1]; // [B]
    const float* start  = (const float*)d_in[2]; // [S]
    const float* stop   = (const float*)d_in[3]; // [S]
    const float* trans  = (const float*)d_in[4]; // [S, S]
    float*       out    = (float*)d_out;         // [B]

    crf_fwd_v4<<<BATCH, NS, 0, stream>>>(em, seqlen, start, stop, trans, out);
}